// Round 12
// baseline (271.476 us; speedup 1.0000x reference)
//
#include <hip/hip_runtime.h>

typedef unsigned short u16;
typedef short bf16x8 __attribute__((ext_vector_type(8)));
typedef float f32x4 __attribute__((ext_vector_type(4)));

#define S_LEN 4096
#define NHEADS 16
#define NKVH 4
#define HDIM 128
#define HID 2048
#define NQKV 3072

__device__ __forceinline__ u16 f2bf(float x) {
  union { float f; unsigned u; } v; v.f = x;
  unsigned r = v.u + 0x7fffu + ((v.u >> 16) & 1u);
  return (u16)(r >> 16);
}
__device__ __forceinline__ float bf2f(u16 x) {
  union { unsigned u; float f; } v; v.u = ((unsigned)x) << 16;
  return v.f;
}
// async global->LDS, 16B per lane; lds ptr must be wave-uniform, data lands at base + lane*16
__device__ __forceinline__ void async16(u16* lds, const u16* g) {
  __builtin_amdgcn_global_load_lds((const __attribute__((address_space(1))) void*)g,
                                   (__attribute__((address_space(3))) void*)lds, 16, 0, 0);
}

// ---------------- fused cast fp32 -> bf16 for all 5 inputs (dsts contiguous in ws) ------
// segments (float4 units): hs 2097152 | wq 1048576 | wk 262144 | wv 262144 | wo 1048576
__global__ __launch_bounds__(256) void cast_all(const float* __restrict__ hs,
                                                const float* __restrict__ wq,
                                                const float* __restrict__ wk,
                                                const float* __restrict__ wv,
                                                const float* __restrict__ wo,
                                                u16* __restrict__ ws) {
  int i = blockIdx.x * 256 + threadIdx.x;   // 0 .. 4718592-1
  const float* src; int si;
  if (i < 2097152)      { src = hs; si = i; }
  else if (i < 3145728) { src = wq; si = i - 2097152; }
  else if (i < 3407872) { src = wk; si = i - 3145728; }
  else if (i < 3670016) { src = wv; si = i - 3407872; }
  else                  { src = wo; si = i - 3670016; }
  float4 v = ((const float4*)src)[si];
  ushort4 o;
  o.x = f2bf(v.x); o.y = f2bf(v.y); o.z = f2bf(v.z); o.w = f2bf(v.w);
  ((ushort4*)ws)[i] = o;
}

// ---------------- GEMM: C[M][N] = A[M][K] * B[N][K]^T, bf16 in, fp32 acc ----------------
// 128x128 tile, BK=64, 4 waves each 64x64, 16x16x32 mfma. (r10 lesson: XCD swizzle doubled
// FETCH with zero time change -> structure-bound; default dispatch order restored.)
// LDS layout: 16B chunks, slot = m*8 + (c ^ (m&7))  (c = k-chunk 0..7) -> conflict-free b128 frag reads.
template<bool OUT_BF16>
__global__ __launch_bounds__(256) void gemm_bt(const u16* __restrict__ A, const u16* __restrict__ B,
                                               void* __restrict__ Cp, int M, int N, int K) {
  __shared__ __align__(16) u16 As[128 * 64];
  __shared__ __align__(16) u16 Bs[128 * 64];
  const int tid = threadIdx.x;
  const int w = tid >> 6, l = tid & 63;
  const int quad = l >> 4, l16 = l & 15;
  const int bm = blockIdx.x, bn = blockIdx.y;
  const int wr = w & 1, wc = w >> 1;

  const size_t abase = (size_t)bm * 128 * K;
  const size_t bbase = (size_t)bn * 128 * K;

  f32x4 acc[4][4];
  for (int i = 0; i < 4; ++i)
    for (int j = 0; j < 4; ++j) acc[i][j] = f32x4{0.f, 0.f, 0.f, 0.f};

  int sm[4], sc[4];
  for (int j = 0; j < 4; ++j) {
    int slot = (w * 4 + j) * 64 + l;
    sm[j] = slot >> 3;
    sc[j] = (slot & 7) ^ (sm[j] & 7);
  }
  int aoff[2][4], boff[2][4];
  for (int ksi = 0; ksi < 2; ++ksi) {
    int cb = ksi * 4 + quad;
    for (int mt = 0; mt < 4; ++mt) {
      int m = wr * 64 + mt * 16 + l16;
      aoff[ksi][mt] = (m * 8 + (cb ^ (m & 7))) * 8;
      int n = wc * 64 + mt * 16 + l16;
      boff[ksi][mt] = (n * 8 + (cb ^ (n & 7))) * 8;
    }
  }

  for (int kt = 0; kt < K; kt += 64) {
    __syncthreads();
    for (int j = 0; j < 4; ++j) {
      async16(&As[(w * 4 + j) * 64 * 8], A + abase + (size_t)sm[j] * K + kt + sc[j] * 8);
      async16(&Bs[(w * 4 + j) * 64 * 8], B + bbase + (size_t)sm[j] * K + kt + sc[j] * 8);
    }
    __syncthreads();
    for (int ksi = 0; ksi < 2; ++ksi) {
      bf16x8 af[4], bv[4];
      for (int mt = 0; mt < 4; ++mt) {
        af[mt] = *(const bf16x8*)&As[aoff[ksi][mt]];
        bv[mt] = *(const bf16x8*)&Bs[boff[ksi][mt]];
      }
      for (int mt = 0; mt < 4; ++mt)
        for (int nt = 0; nt < 4; ++nt)
          acc[mt][nt] = __builtin_amdgcn_mfma_f32_16x16x32_bf16(af[mt], bv[nt], acc[mt][nt], 0, 0, 0);
    }
  }

  const int row_base = bm * 128 + wr * 64;
  const int col_base = bn * 128 + wc * 64;
  for (int mt = 0; mt < 4; ++mt)
    for (int nt = 0; nt < 4; ++nt) {
      int col = col_base + nt * 16 + l16;
      for (int r = 0; r < 4; ++r) {
        int row = row_base + mt * 16 + quad * 4 + r;
        float v = acc[mt][nt][r];
        if (OUT_BF16) ((u16*)Cp)[(size_t)row * N + col] = f2bf(v);
        else          ((float*)Cp)[(size_t)row * N + col] = v;
      }
    }
}

// ---------------- fused RoPE-scatter (Q pre-scaled by 1/sqrt(d)) + V transpose ----------
// blocks 0..2559: rope (4096*20*8 threads); blocks 2560..3071: vtrans (64x8 tile grid)
__global__ __launch_bounds__(256) void rope_vtrans(const u16* __restrict__ qkv,
                                                   const float* __restrict__ cosp,
                                                   const float* __restrict__ sinp,
                                                   u16* __restrict__ Q, u16* __restrict__ Kd,
                                                   u16* __restrict__ Vt) {
  __shared__ u16 tile[64][65];
  const int bid = blockIdx.x;
  const int tid = threadIdx.x;
  if (bid < 2560) {
    const float SCALE = 0.08838834764831845f;
    int idx = bid * 256 + tid;  // total 4096*20*8
    int d8 = (idx & 7) * 8;
    int hh = (idx >> 3) % 20;
    int s = idx / 160;
    size_t base = (size_t)s * NQKV + hh * 128;

    ushort4 xa = *(const ushort4*)&qkv[base + d8];
    ushort4 xb = *(const ushort4*)&qkv[base + d8 + 4];
    ushort4 ya = *(const ushort4*)&qkv[base + d8 + 64];
    ushort4 yb = *(const ushort4*)&qkv[base + d8 + 68];
    float x[8] = { bf2f(xa.x), bf2f(xa.y), bf2f(xa.z), bf2f(xa.w),
                   bf2f(xb.x), bf2f(xb.y), bf2f(xb.z), bf2f(xb.w) };
    float y[8] = { bf2f(ya.x), bf2f(ya.y), bf2f(ya.z), bf2f(ya.w),
                   bf2f(yb.x), bf2f(yb.y), bf2f(yb.z), bf2f(yb.w) };

    const float* cp = cosp + s * 128 + d8;
    const float* sp = sinp + s * 128 + d8;
    float4 c0 = *(const float4*)(cp);
    float4 c1 = *(const float4*)(cp + 4);
    float4 c2 = *(const float4*)(cp + 64);
    float4 c3 = *(const float4*)(cp + 68);
    float4 s0 = *(const float4*)(sp);
    float4 s1 = *(const float4*)(sp + 4);
    float4 s2 = *(const float4*)(sp + 64);
    float4 s3 = *(const float4*)(sp + 68);
    float cl[8] = { c0.x, c0.y, c0.z, c0.w, c1.x, c1.y, c1.z, c1.w };
    float sl[8] = { s0.x, s0.y, s0.z, s0.w, s1.x, s1.y, s1.z, s1.w };
    float ch[8] = { c2.x, c2.y, c2.z, c2.w, c3.x, c3.y, c3.z, c3.w };
    float sh[8] = { s2.x, s2.y, s2.z, s2.w, s3.x, s3.y, s3.z, s3.w };

    const float g = (hh < NHEADS) ? SCALE : 1.0f;  // fold softmax scale into Q
    u16 o1[8], o2[8];
#pragma unroll
    for (int j = 0; j < 8; ++j) {
      o1[j] = f2bf((x[j] * cl[j] - y[j] * sl[j]) * g);
      o2[j] = f2bf((y[j] * ch[j] + x[j] * sh[j]) * g);
    }
    u16* dst = (hh < NHEADS) ? (Q + ((size_t)hh * S_LEN + s) * HDIM)
                             : (Kd + ((size_t)(hh - NHEADS) * S_LEN + s) * HDIM);
    *(ushort4*)&dst[d8]      = ushort4{o1[0], o1[1], o1[2], o1[3]};
    *(ushort4*)&dst[d8 + 4]  = ushort4{o1[4], o1[5], o1[6], o1[7]};
    *(ushort4*)&dst[d8 + 64] = ushort4{o2[0], o2[1], o2[2], o2[3]};
    *(ushort4*)&dst[d8 + 68] = ushort4{o2[4], o2[5], o2[6], o2[7]};
  } else {
    // V transpose: qkv[s][2560+j] -> Vt[j][s]
    int vb = bid - 2560;          // 0..511
    int s0 = (vb & 63) * 64;
    int j0 = (vb >> 6) * 64;
    for (int it = 0; it < 16; ++it) {
      int lin = it * 256 + tid;
      int sr = lin >> 6, jc = lin & 63;
      tile[sr][jc] = qkv[(size_t)(s0 + sr) * NQKV + 2560 + j0 + jc];
    }
    __syncthreads();
    for (int it = 0; it < 16; ++it) {
      int lin = it * 256 + tid;
      int dr = lin >> 6, sc = lin & 63;
      Vt[(size_t)(j0 + dr) * S_LEN + s0 + sc] = tile[sc][dr];
    }
  }
}

// ---------------- block-sparse flash attention: 128-row q-tile, staged K/V dbuf ---------
// Each block covers TWO 64-row t-blocks (t0=2tt: waves 0,1; t1=2tt+1: waves 2,3), iterating
// the UNION K-block list; waves skip (wave-uniform) the kb's not in their own sel set.
// Halves staging events + K/V global traffic vs 64-row tiles; identical per-row math/order.
// K-frag reads shared across each wave's two 16-row sub-tiles; Ps reused per sub-tile
// (same-wave sequential, no barrier). LDS 73KB -> 2 blocks/CU. No-max softmax; Q pre-scaled.
// grid (32 tt, 16 h), 256 thr.
__global__ __launch_bounds__(256) void attn_kernel(const u16* __restrict__ Q, const u16* __restrict__ K,
                                                   const u16* __restrict__ Vt, u16* __restrict__ Aout) {
  const float NEGF = -30000.0f;  // exp -> exact 0; no overflow in x*log2e intermediate
  const int tt = blockIdx.x, h = blockIdx.y;
  const int kvh = h >> 2;
  const int tid = threadIdx.x;
  const int w = tid >> 6, l = tid & 63, quad = l >> 4, l16 = l & 15;
  const int th = tt * 2 + (w >> 1);   // this wave's 64-row t-block
  const int sub = w & 1;              // which 32-row half of th this wave owns

  __shared__ __align__(16) u16 Ks[2][64 * 128];  // slot = m*16 + (c ^ (m&15))
  __shared__ __align__(16) u16 Vs[2][128 * 64];  // [d][s], slot = d*8 + (c ^ (d&7))
  __shared__ __align__(16) u16 Ps[4 * 16 * 72];  // per-wave 16 rows, pad to 72 (reused per sub-tile)

  // union sel list for t0 and t1 (globals identical for both: (2tt)>>2 == (2tt+1)>>2)
  const int t1 = 2 * tt + 1;
  const int g1 = (t1 >> 2) << 2, g0 = g1 - 4;
  int sel[8]; int nsel = 0;
  {
    int lo_u = 2 * tt - 4; if (lo_u < 0) lo_u = 0;
    if (g0 >= 0 && g0 < lo_u) sel[nsel++] = g0;
    for (int b = lo_u; b <= t1; ++b) sel[nsel++] = b;
  }
  const int lo_w = (th - 4 < 0) ? 0 : th - 4;

  // Q fragments -> registers: rows tt*128 + w*32 + mt*16 + l16 (16B contiguous chunks)
  bf16x8 qf[2][4];
#pragma unroll
  for (int mt = 0; mt < 2; ++mt) {
    const u16* qptr = Q + ((size_t)h * S_LEN + tt * 128 + w * 32 + mt * 16 + l16) * HDIM + quad * 8;
#pragma unroll
    for (int ks = 0; ks < 4; ++ks) qf[mt][ks] = *(const bf16x8*)(qptr + ks * 32);
  }

  // per-wave staging of K/V block kb into buffer b (whole 256-thr block cooperates)
  const int slot0 = w * 4 * 64 + l;
#define STAGEKV(b, kb) do { \
    const size_t kbase = ((size_t)kvh * S_LEN + (kb) * 64) * HDIM; \
    const size_t vbase = (size_t)kvh * HDIM * S_LEN + (kb) * 64; \
    _Pragma("unroll") \
    for (int j_ = 0; j_ < 4; ++j_) { \
      int slot = slot0 + j_ * 64; \
      int mk = slot >> 4; \
      int ck = (slot & 15) ^ (mk & 15); \
      async16(&Ks[b][(w * 4 + j_) * 64 * 8], K + kbase + mk * 128 + ck * 8); \
      int dv = slot >> 3; \
      int cv = (slot & 7) ^ (dv & 7); \
      async16(&Vs[b][(w * 4 + j_) * 64 * 8], Vt + vbase + (size_t)dv * S_LEN + cv * 8); \
    } } while (0)

  STAGEKV(0, sel[0]);
  __syncthreads();

  float l_run[2][4];
  for (int mt = 0; mt < 2; ++mt)
    for (int r = 0; r < 4; ++r) l_run[mt][r] = 0.f;
  f32x4 oacc[2][8];
  for (int mt = 0; mt < 2; ++mt)
    for (int i = 0; i < 8; ++i) oacc[mt][i] = f32x4{0.f, 0.f, 0.f, 0.f};

  for (int ib = 0; ib < nsel; ++ib) {
    const int kb = sel[ib];
    const int cur = ib & 1;
    if (ib + 1 < nsel) STAGEKV(cur ^ 1, sel[ib + 1]);   // prefetch next (drained at this iter's barrier)

    // wave-uniform validity: kb in sel(th)?
    const bool valid = (kb >= lo_w && kb <= th) || (kb == g0 && g0 >= 0) || (kb == g1);
    if (valid) {
      // S = Q K^T for both 16-row sub-tiles (K fragments shared)
      f32x4 sacc[2][4];
      for (int mt = 0; mt < 2; ++mt)
        for (int nt = 0; nt < 4; ++nt) sacc[mt][nt] = f32x4{0.f, 0.f, 0.f, 0.f};
#pragma unroll
      for (int ks = 0; ks < 4; ++ks) {
        int cb = ks * 4 + quad;
#pragma unroll
        for (int nt = 0; nt < 4; ++nt) {
          int n = nt * 16 + l16;
          bf16x8 bv = *(const bf16x8*)&Ks[cur][(n * 16 + (cb ^ (n & 15))) * 8];
          sacc[0][nt] = __builtin_amdgcn_mfma_f32_16x16x32_bf16(qf[0][ks], bv, sacc[0][nt], 0, 0, 0);
          sacc[1][nt] = __builtin_amdgcn_mfma_f32_16x16x32_bf16(qf[1][ks], bv, sacc[1][nt], 0, 0, 0);
        }
      }

      const bool diag = (kb == th);
#pragma unroll
      for (int mt = 0; mt < 2; ++mt) {
        // softmax for this sub-tile's 16 rows -> Ps (per-wave region, sequential reuse)
        for (int r = 0; r < 4; ++r) {
          int qrow = sub * 32 + mt * 16 + quad * 4 + r;   // row within the 64-row t-block
          float sum = 0.f;
          for (int nt = 0; nt < 4; ++nt) {
            float v = sacc[mt][nt][r];
            if (diag && (nt * 16 + l16) > qrow) v = NEGF;
            float p = __expf(v);
            sum += p;
            Ps[(w * 16 + quad * 4 + r) * 72 + nt * 16 + l16] = f2bf(p);
          }
          for (int off = 1; off < 16; off <<= 1) sum += __shfl_xor(sum, off);
          l_run[mt][r] += sum;
        }
        // O += P V for this sub-tile
#pragma unroll
        for (int ksv = 0; ksv < 64; ksv += 32) {
          bf16x8 pf = *(const bf16x8*)&Ps[(w * 16 + l16) * 72 + ksv + quad * 8];
          int cb = (ksv >> 3) + quad;
#pragma unroll
          for (int nt = 0; nt < 8; ++nt) {
            int n = nt * 16 + l16;
            bf16x8 vv = *(const bf16x8*)&Vs[cur][(n * 8 + (cb ^ (n & 7))) * 8];
            oacc[mt][nt] = __builtin_amdgcn_mfma_f32_16x16x32_bf16(pf, vv, oacc[mt][nt], 0, 0, 0);
          }
        }
      }
    }

    __syncthreads();   // drains this iter's prefetch (vmcnt) + all waves' buf reads (lgkm)
  }
#undef STAGEKV

#pragma unroll
  for (int mt = 0; mt < 2; ++mt) {
    float inv[4];
    for (int r = 0; r < 4; ++r) inv[r] = 1.f / l_run[mt][r];
    const int srow = tt * 128 + w * 32 + mt * 16 + quad * 4;
    for (int nt = 0; nt < 8; ++nt) {
      int col = h * 128 + nt * 16 + l16;
      for (int r = 0; r < 4; ++r)
        Aout[(size_t)(srow + r) * HID + col] = f2bf(oacc[mt][nt][r] * inv[r]);
    }
  }
}

extern "C" void kernel_launch(void* const* d_in, const int* in_sizes, int n_in,
                              void* d_out, int out_size, void* d_ws, size_t ws_size,
                              hipStream_t stream) {
  const float* hs   = (const float*)d_in[0];
  const float* cosp = (const float*)d_in[1];
  const float* sinp = (const float*)d_in[2];
  const float* wq   = (const float*)d_in[3];
  const float* wk   = (const float*)d_in[4];
  const float* wv   = (const float*)d_in[5];
  const float* wo   = (const float*)d_in[6];

  u16* hsb = (u16*)d_ws;                        // 4096*2048
  u16* W   = hsb + (size_t)S_LEN * HID;         // 3072*2048 (wq;wk;wv)
  u16* wob = W + (size_t)NQKV * HID;            // 2048*2048
  u16* qkv = wob + (size_t)HID * HID;           // 4096*3072
  u16* Qm  = qkv + (size_t)S_LEN * NQKV;        // 16*4096*128
  u16* Km  = Qm + (size_t)NHEADS * S_LEN * HDIM; // 4*4096*128
  u16* Vt  = Km + (size_t)NKVH * S_LEN * HDIM;  // 4*128*4096
  u16* att = Vt + (size_t)NKVH * HDIM * S_LEN;  // 4096*2048

  cast_all<<<18432, 256, 0, stream>>>(hs, wq, wk, wv, wo, (u16*)d_ws);

  gemm_bt<true><<<dim3(32, 24), 256, 0, stream>>>(hsb, W, (void*)qkv, 4096, 3072, 2048);
  rope_vtrans<<<3072, 256, 0, stream>>>(qkv, cosp, sinp, Qm, Km, Vt);
  attn_kernel<<<dim3(32, 16), 256, 0, stream>>>(Qm, Km, Vt, att);
  gemm_bt<false><<<dim3(32, 16), 256, 0, stream>>>(att, wob, d_out, 4096, 2048, 2048);
}

// Round 13
// 260.956 us; speedup vs baseline: 1.0403x; 1.0403x over previous
//
#include <hip/hip_runtime.h>

typedef unsigned short u16;
typedef short bf16x8 __attribute__((ext_vector_type(8)));
typedef float f32x4 __attribute__((ext_vector_type(4)));

#define S_LEN 4096
#define NHEADS 16
#define NKVH 4
#define HDIM 128
#define HID 2048
#define NQKV 3072

__device__ __forceinline__ u16 f2bf(float x) {
  union { float f; unsigned u; } v; v.f = x;
  unsigned r = v.u + 0x7fffu + ((v.u >> 16) & 1u);
  return (u16)(r >> 16);
}
__device__ __forceinline__ float bf2f(u16 x) {
  union { unsigned u; float f; } v; v.u = ((unsigned)x) << 16;
  return v.f;
}
// async global->LDS, 16B per lane; lds ptr must be wave-uniform, data lands at base + lane*16
__device__ __forceinline__ void async16(u16* lds, const u16* g) {
  __builtin_amdgcn_global_load_lds((const __attribute__((address_space(1))) void*)g,
                                   (__attribute__((address_space(3))) void*)lds, 16, 0, 0);
}

// ---------------- fused cast fp32 -> bf16 for all 5 inputs (dsts contiguous in ws) ------
// segments (float4 units): hs 2097152 | wq 1048576 | wk 262144 | wv 262144 | wo 1048576
// G11: memory-bound -> 2048 blocks, grid-stride (9 iters/thread) instead of 18432 one-shot.
__global__ __launch_bounds__(256) void cast_all(const float* __restrict__ hs,
                                                const float* __restrict__ wq,
                                                const float* __restrict__ wk,
                                                const float* __restrict__ wv,
                                                const float* __restrict__ wo,
                                                u16* __restrict__ ws) {
  const int stride = 2048 * 256;
  for (int i = blockIdx.x * 256 + threadIdx.x; i < 4718592; i += stride) {
    const float* src; int si;
    if (i < 2097152)      { src = hs; si = i; }
    else if (i < 3145728) { src = wq; si = i - 2097152; }
    else if (i < 3407872) { src = wk; si = i - 3145728; }
    else if (i < 3670016) { src = wv; si = i - 3407872; }
    else                  { src = wo; si = i - 3670016; }
    float4 v = ((const float4*)src)[si];
    ushort4 o;
    o.x = f2bf(v.x); o.y = f2bf(v.y); o.z = f2bf(v.z); o.w = f2bf(v.w);
    ((ushort4*)ws)[i] = o;
  }
}

// ---------------- GEMM: C[M][N] = A[M][K] * B[N][K]^T, bf16 in, fp32 acc ----------------
// 128x128 tile, BK=64, 4 waves each 64x64, 16x16x32 mfma. (r10: XCD swizzle doubled FETCH
// with zero time change -> structure-bound; default dispatch order.)
// LDS layout: 16B chunks, slot = m*8 + (c ^ (m&7))  (c = k-chunk 0..7) -> conflict-free b128 frag reads.
template<bool OUT_BF16>
__global__ __launch_bounds__(256) void gemm_bt(const u16* __restrict__ A, const u16* __restrict__ B,
                                               void* __restrict__ Cp, int M, int N, int K) {
  __shared__ __align__(16) u16 As[128 * 64];
  __shared__ __align__(16) u16 Bs[128 * 64];
  const int tid = threadIdx.x;
  const int w = tid >> 6, l = tid & 63;
  const int quad = l >> 4, l16 = l & 15;
  const int bm = blockIdx.x, bn = blockIdx.y;
  const int wr = w & 1, wc = w >> 1;

  const size_t abase = (size_t)bm * 128 * K;
  const size_t bbase = (size_t)bn * 128 * K;

  f32x4 acc[4][4];
  for (int i = 0; i < 4; ++i)
    for (int j = 0; j < 4; ++j) acc[i][j] = f32x4{0.f, 0.f, 0.f, 0.f};

  int sm[4], sc[4];
  for (int j = 0; j < 4; ++j) {
    int slot = (w * 4 + j) * 64 + l;
    sm[j] = slot >> 3;
    sc[j] = (slot & 7) ^ (sm[j] & 7);
  }
  int aoff[2][4], boff[2][4];
  for (int ksi = 0; ksi < 2; ++ksi) {
    int cb = ksi * 4 + quad;
    for (int mt = 0; mt < 4; ++mt) {
      int m = wr * 64 + mt * 16 + l16;
      aoff[ksi][mt] = (m * 8 + (cb ^ (m & 7))) * 8;
      int n = wc * 64 + mt * 16 + l16;
      boff[ksi][mt] = (n * 8 + (cb ^ (n & 7))) * 8;
    }
  }

  for (int kt = 0; kt < K; kt += 64) {
    __syncthreads();
    for (int j = 0; j < 4; ++j) {
      async16(&As[(w * 4 + j) * 64 * 8], A + abase + (size_t)sm[j] * K + kt + sc[j] * 8);
      async16(&Bs[(w * 4 + j) * 64 * 8], B + bbase + (size_t)sm[j] * K + kt + sc[j] * 8);
    }
    __syncthreads();
    for (int ksi = 0; ksi < 2; ++ksi) {
      bf16x8 af[4], bv[4];
      for (int mt = 0; mt < 4; ++mt) {
        af[mt] = *(const bf16x8*)&As[aoff[ksi][mt]];
        bv[mt] = *(const bf16x8*)&Bs[boff[ksi][mt]];
      }
      for (int mt = 0; mt < 4; ++mt)
        for (int nt = 0; nt < 4; ++nt)
          acc[mt][nt] = __builtin_amdgcn_mfma_f32_16x16x32_bf16(af[mt], bv[nt], acc[mt][nt], 0, 0, 0);
    }
  }

  const int row_base = bm * 128 + wr * 64;
  const int col_base = bn * 128 + wc * 64;
  for (int mt = 0; mt < 4; ++mt)
    for (int nt = 0; nt < 4; ++nt) {
      int col = col_base + nt * 16 + l16;
      for (int r = 0; r < 4; ++r) {
        int row = row_base + mt * 16 + quad * 4 + r;
        float v = acc[mt][nt][r];
        if (OUT_BF16) ((u16*)Cp)[(size_t)row * N + col] = f2bf(v);
        else          ((float*)Cp)[(size_t)row * N + col] = v;
      }
    }
}

// ---------------- fused RoPE-scatter (Q pre-scaled by 1/sqrt(d)) + V transpose ----------
// blocks 0..2559: rope (4096*20*8 threads); blocks 2560..3071: vtrans (64x8 tile grid)
__global__ __launch_bounds__(256) void rope_vtrans(const u16* __restrict__ qkv,
                                                   const float* __restrict__ cosp,
                                                   const float* __restrict__ sinp,
                                                   u16* __restrict__ Q, u16* __restrict__ Kd,
                                                   u16* __restrict__ Vt) {
  __shared__ u16 tile[64][65];
  const int bid = blockIdx.x;
  const int tid = threadIdx.x;
  if (bid < 2560) {
    const float SCALE = 0.08838834764831845f;
    int idx = bid * 256 + tid;  // total 4096*20*8
    int d8 = (idx & 7) * 8;
    int hh = (idx >> 3) % 20;
    int s = idx / 160;
    size_t base = (size_t)s * NQKV + hh * 128;

    ushort4 xa = *(const ushort4*)&qkv[base + d8];
    ushort4 xb = *(const ushort4*)&qkv[base + d8 + 4];
    ushort4 ya = *(const ushort4*)&qkv[base + d8 + 64];
    ushort4 yb = *(const ushort4*)&qkv[base + d8 + 68];
    float x[8] = { bf2f(xa.x), bf2f(xa.y), bf2f(xa.z), bf2f(xa.w),
                   bf2f(xb.x), bf2f(xb.y), bf2f(xb.z), bf2f(xb.w) };
    float y[8] = { bf2f(ya.x), bf2f(ya.y), bf2f(ya.z), bf2f(ya.w),
                   bf2f(yb.x), bf2f(yb.y), bf2f(yb.z), bf2f(yb.w) };

    const float* cp = cosp + s * 128 + d8;
    const float* sp = sinp + s * 128 + d8;
    float4 c0 = *(const float4*)(cp);
    float4 c1 = *(const float4*)(cp + 4);
    float4 c2 = *(const float4*)(cp + 64);
    float4 c3 = *(const float4*)(cp + 68);
    float4 s0 = *(const float4*)(sp);
    float4 s1 = *(const float4*)(sp + 4);
    float4 s2 = *(const float4*)(sp + 64);
    float4 s3 = *(const float4*)(sp + 68);
    float cl[8] = { c0.x, c0.y, c0.z, c0.w, c1.x, c1.y, c1.z, c1.w };
    float sl[8] = { s0.x, s0.y, s0.z, s0.w, s1.x, s1.y, s1.z, s1.w };
    float ch[8] = { c2.x, c2.y, c2.z, c2.w, c3.x, c3.y, c3.z, c3.w };
    float sh[8] = { s2.x, s2.y, s2.z, s2.w, s3.x, s3.y, s3.z, s3.w };

    const float g = (hh < NHEADS) ? SCALE : 1.0f;  // fold softmax scale into Q
    u16 o1[8], o2[8];
#pragma unroll
    for (int j = 0; j < 8; ++j) {
      o1[j] = f2bf((x[j] * cl[j] - y[j] * sl[j]) * g);
      o2[j] = f2bf((y[j] * ch[j] + x[j] * sh[j]) * g);
    }
    u16* dst = (hh < NHEADS) ? (Q + ((size_t)hh * S_LEN + s) * HDIM)
                             : (Kd + ((size_t)(hh - NHEADS) * S_LEN + s) * HDIM);
    *(ushort4*)&dst[d8]      = ushort4{o1[0], o1[1], o1[2], o1[3]};
    *(ushort4*)&dst[d8 + 4]  = ushort4{o1[4], o1[5], o1[6], o1[7]};
    *(ushort4*)&dst[d8 + 64] = ushort4{o2[0], o2[1], o2[2], o2[3]};
    *(ushort4*)&dst[d8 + 68] = ushort4{o2[4], o2[5], o2[6], o2[7]};
  } else {
    // V transpose: qkv[s][2560+j] -> Vt[j][s]
    int vb = bid - 2560;          // 0..511
    int s0 = (vb & 63) * 64;
    int j0 = (vb >> 6) * 64;
    for (int it = 0; it < 16; ++it) {
      int lin = it * 256 + tid;
      int sr = lin >> 6, jc = lin & 63;
      tile[sr][jc] = qkv[(size_t)(s0 + sr) * NQKV + 2560 + j0 + jc];
    }
    __syncthreads();
    for (int it = 0; it < 16; ++it) {
      int lin = it * 256 + tid;
      int dr = lin >> 6, sc = lin & 63;
      Vt[(size_t)(j0 + dr) * S_LEN + s0 + sc] = tile[sc][dr];
    }
  }
}

// ---------------- block-sparse flash attention: staged K/V, double-buffered (r9 best) ---
// Q in registers; K/V double-buffered in LDS (73KB, 2 blocks/CU); 2-phase: STAGE(next) ->
// compute(cur) -> one __syncthreads. No-max softmax (Q pre-scaled at RoPE).
// grid (64 qblocks, 16 heads), 256 thr. Wave w owns q rows w*16..w*16+15.
// (r12: 128-row q-tile regressed ~17us -> reverted to this exact structure.)
__global__ __launch_bounds__(256) void attn_kernel(const u16* __restrict__ Q, const u16* __restrict__ K,
                                                   const u16* __restrict__ Vt, u16* __restrict__ Aout) {
  const float NEGF = -30000.0f;  // exp -> exact 0; no overflow in x*log2e intermediate
  const int t = blockIdx.x, h = blockIdx.y;
  const int kvh = h >> 2;
  const int tid = threadIdx.x;
  const int w = tid >> 6, l = tid & 63, quad = l >> 4, l16 = l & 15;

  __shared__ __align__(16) u16 Ks[2][64 * 128];  // slot = m*16 + (c ^ (m&15))
  __shared__ __align__(16) u16 Vs[2][128 * 64];  // [d][s], slot = d*8 + (c ^ (d&7))
  __shared__ __align__(16) u16 Ps[4 * 16 * 72];  // per-wave 16 rows, pad to 72

  int sel[7]; int nsel = 0;
  {
    int g1 = (t >> 2) << 2, g0 = g1 - 4;
    int lo = t - 4; if (lo < 0) lo = 0;
    if (g0 >= 0 && g0 < lo) sel[nsel++] = g0;
    if (g1 < lo) sel[nsel++] = g1;
    for (int b = lo; b <= t; ++b) sel[nsel++] = b;
  }

  // Q fragments -> registers (row mq, k-chunk ks*32 + quad*8; 16B contiguous). One-time.
  const int mq = w * 16 + l16;
  const u16* qptr = Q + ((size_t)h * S_LEN + t * 64 + mq) * HDIM + quad * 8;
  bf16x8 qf[4];
#pragma unroll
  for (int ks = 0; ks < 4; ++ks) qf[ks] = *(const bf16x8*)(qptr + ks * 32);

  // per-wave staging of K/V block kb into buffer b
  const int slot0 = w * 4 * 64 + l;
#define STAGEKV(b, kb) do { \
    const size_t kbase = ((size_t)kvh * S_LEN + (kb) * 64) * HDIM; \
    const size_t vbase = (size_t)kvh * HDIM * S_LEN + (kb) * 64; \
    _Pragma("unroll") \
    for (int j_ = 0; j_ < 4; ++j_) { \
      int slot = slot0 + j_ * 64; \
      int mk = slot >> 4; \
      int ck = (slot & 15) ^ (mk & 15); \
      async16(&Ks[b][(w * 4 + j_) * 64 * 8], K + kbase + mk * 128 + ck * 8); \
      int dv = slot >> 3; \
      int cv = (slot & 7) ^ (dv & 7); \
      async16(&Vs[b][(w * 4 + j_) * 64 * 8], Vt + vbase + (size_t)dv * S_LEN + cv * 8); \
    } } while (0)

  STAGEKV(0, sel[0]);
  __syncthreads();

  float l_run[4];
  for (int r = 0; r < 4; ++r) l_run[r] = 0.f;
  f32x4 oacc[8];
  for (int i = 0; i < 8; ++i) oacc[i] = f32x4{0.f, 0.f, 0.f, 0.f};

  for (int ib = 0; ib < nsel; ++ib) {
    const int kb = sel[ib];
    const int cur = ib & 1;
    if (ib + 1 < nsel) STAGEKV(cur ^ 1, sel[ib + 1]);   // prefetch next (drained at this iter's barrier)

    // S = Q K^T for this wave's 16 q rows x 64 key cols (Q pre-scaled)
    f32x4 sacc[4];
    for (int nt = 0; nt < 4; ++nt) sacc[nt] = f32x4{0.f, 0.f, 0.f, 0.f};
#pragma unroll
    for (int ks = 0; ks < 4; ++ks) {
      int cb = ks * 4 + quad;
#pragma unroll
      for (int nt = 0; nt < 4; ++nt) {
        int n = nt * 16 + l16;
        bf16x8 bv = *(const bf16x8*)&Ks[cur][(n * 16 + (cb ^ (n & 15))) * 8];
        sacc[nt] = __builtin_amdgcn_mfma_f32_16x16x32_bf16(qf[ks], bv, sacc[nt], 0, 0, 0);
      }
    }

    const bool diag = (kb == t);
    for (int r = 0; r < 4; ++r) {
      int qrow = w * 16 + quad * 4 + r;
      float sum = 0.f;
      for (int nt = 0; nt < 4; ++nt) {
        float v = sacc[nt][r];
        if (diag && (nt * 16 + l16) > qrow) v = NEGF;
        float p = __expf(v);
        sum += p;
        Ps[(w * 16 + quad * 4 + r) * 72 + nt * 16 + l16] = f2bf(p);
      }
      for (int off = 1; off < 16; off <<= 1) sum += __shfl_xor(sum, off);
      l_run[r] += sum;
    }

    // O += P V   (P from per-wave LDS region, A-operand layout; V^T from Vs)
#pragma unroll
    for (int ks = 0; ks < 64; ks += 32) {
      bf16x8 pf = *(const bf16x8*)&Ps[(w * 16 + l16) * 72 + ks + quad * 8];
      int cb = (ks >> 3) + quad;
#pragma unroll
      for (int nt = 0; nt < 8; ++nt) {
        int n = nt * 16 + l16;
        bf16x8 vv = *(const bf16x8*)&Vs[cur][(n * 8 + (cb ^ (n & 7))) * 8];
        oacc[nt] = __builtin_amdgcn_mfma_f32_16x16x32_bf16(pf, vv, oacc[nt], 0, 0, 0);
      }
    }

    __syncthreads();   // drains this iter's prefetch (vmcnt) + all waves' buf reads (lgkm)
  }
#undef STAGEKV

  float inv[4];
  for (int r = 0; r < 4; ++r) inv[r] = 1.f / l_run[r];
  const int srow = t * 64 + w * 16 + quad * 4;
  for (int nt = 0; nt < 8; ++nt) {
    int col = h * 128 + nt * 16 + l16;
    for (int r = 0; r < 4; ++r)
      Aout[(size_t)(srow + r) * HID + col] = f2bf(oacc[nt][r] * inv[r]);
  }
}

extern "C" void kernel_launch(void* const* d_in, const int* in_sizes, int n_in,
                              void* d_out, int out_size, void* d_ws, size_t ws_size,
                              hipStream_t stream) {
  const float* hs   = (const float*)d_in[0];
  const float* cosp = (const float*)d_in[1];
  const float* sinp = (const float*)d_in[2];
  const float* wq   = (const float*)d_in[3];
  const float* wk   = (const float*)d_in[4];
  const float* wv   = (const float*)d_in[5];
  const float* wo   = (const float*)d_in[6];

  u16* hsb = (u16*)d_ws;                        // 4096*2048
  u16* W   = hsb + (size_t)S_LEN * HID;         // 3072*2048 (wq;wk;wv)
  u16* wob = W + (size_t)NQKV * HID;            // 2048*2048
  u16* qkv = wob + (size_t)HID * HID;           // 4096*3072
  u16* Qm  = qkv + (size_t)S_LEN * NQKV;        // 16*4096*128
  u16* Km  = Qm + (size_t)NHEADS * S_LEN * HDIM; // 4*4096*128
  u16* Vt  = Km + (size_t)NKVH * S_LEN * HDIM;  // 4*128*4096
  u16* att = Vt + (size_t)NKVH * HDIM * S_LEN;  // 4096*2048

  cast_all<<<2048, 256, 0, stream>>>(hs, wq, wk, wv, wo, (u16*)d_ws);

  gemm_bt<true><<<dim3(32, 24), 256, 0, stream>>>(hsb, W, (void*)qkv, 4096, 3072, 2048);
  rope_vtrans<<<3072, 256, 0, stream>>>(qkv, cosp, sinp, Qm, Km, Vt);
  attn_kernel<<<dim3(64, 16), 256, 0, stream>>>(Qm, Km, Vt, att);
  gemm_bt<false><<<dim3(32, 16), 256, 0, stream>>>(att, wob, d_out, 4096, 2048, 2048);
}